// Round 5
// baseline (1502.689 us; speedup 1.0000x reference)
//
#include <hip/hip_runtime.h>
#include <cstddef>

// ---------------------------------------------------------------------------
// Encoder, round 5: round-4 structure with the B-tile LDS stride bug fixed
// (NTILE < VPI case: buffer stride is RB*512 halves, not NTILE*KC).
//  - conflict-free LDS layout: per-1KiB staging block = [chunk][voxel][16B]
//  - B weights staged via VGPR -> ds_write, one tap lookahead; per-tap
//    barrier is lgkmcnt-only so prefetch global loads stay in flight
//  - full __syncthreads only at c-chunk boundaries (halo global_load_lds)
// ---------------------------------------------------------------------------

#define EPSV 1e-5f

typedef _Float16 f16x4 __attribute__((ext_vector_type(4)));
typedef _Float16 f16x8 __attribute__((ext_vector_type(8)));
typedef float f32x4 __attribute__((ext_vector_type(4)));

template <int KC> struct FragSel;
template <> struct FragSel<32> { using T = f16x8; };
template <> struct FragSel<16> { using T = f16x4; };

__device__ __forceinline__ f32x4 mfma16(f16x8 a, f16x8 b, f32x4 c) {
    return __builtin_amdgcn_mfma_f32_16x16x32_f16(a, b, c, 0, 0, 0);
}
__device__ __forceinline__ f32x4 mfma16(f16x4 a, f16x4 b, f32x4 c) {
    return __builtin_amdgcn_mfma_f32_16x16x16f16(a, b, c, 0, 0, 0);
}

__device__ __forceinline__ void gld16(const void* g, void* l) {
    __builtin_amdgcn_global_load_lds(
        (const __attribute__((address_space(1))) unsigned int*)g,
        (__attribute__((address_space(3))) unsigned int*)l, 16, 0, 0);
}

// barrier that only drains LDS ops: keeps prefetch global loads in flight
__device__ __forceinline__ void lgkm_barrier() {
    asm volatile("s_waitcnt lgkmcnt(0)\n\ts_barrier" ::: "memory");
}

// ---------------- mask pooling (with fused counts) ----------------
__global__ __launch_bounds__(256) void pool0_kernel(const int* __restrict__ mask,
                                                    float* __restrict__ mout,
                                                    float* __restrict__ cnt) {
    int voxel = blockIdx.x * 256 + threadIdx.x;          // 4 * 64^3
    int wo = voxel & 63, ho = (voxel >> 6) & 63, dd = (voxel >> 12) & 63, b = voxel >> 18;
    int any = 0;
#pragma unroll
    for (int dz = 0; dz < 2; ++dz)
#pragma unroll
        for (int hy = 0; hy < 2; ++hy)
#pragma unroll
            for (int wx = 0; wx < 2; ++wx) {
                size_t idx = ((size_t)((b * 128 + 2 * dd + dz) * 128 + 2 * ho + hy)) * 128
                             + 2 * wo + wx;
                any |= mask[idx];
            }
    float v = any ? 1.f : 0.f;
    mout[voxel] = v;
    __shared__ float red[256];
    red[threadIdx.x] = v;
    __syncthreads();
    for (int st = 128; st > 0; st >>= 1) {
        if (threadIdx.x < st) red[threadIdx.x] += red[threadIdx.x + st];
        __syncthreads();
    }
    if (threadIdx.x == 0) atomicAdd(cnt, red[0]);
}

__global__ __launch_bounds__(256) void poolf_kernel(const float* __restrict__ min_,
                                                    float* __restrict__ mout,
                                                    int Nout, int lnout,
                                                    float* __restrict__ cnt,
                                                    float* __restrict__ cntb, int lbatch) {
    int voxel = blockIdx.x * 256 + threadIdx.x;
    int Nin = Nout * 2;
    int wo = voxel & (Nout - 1);
    int ho = (voxel >> lnout) & (Nout - 1);
    int dd = (voxel >> (2 * lnout)) & (Nout - 1);
    int b = voxel >> (3 * lnout);
    float mx = 0.f;
#pragma unroll
    for (int dz = 0; dz < 2; ++dz)
#pragma unroll
        for (int hy = 0; hy < 2; ++hy)
#pragma unroll
            for (int wx = 0; wx < 2; ++wx) {
                size_t idx = ((size_t)((b * Nin + 2 * dd + dz) * Nin + 2 * ho + hy)) * Nin
                             + 2 * wo + wx;
                mx = fmaxf(mx, min_[idx]);
            }
    mout[voxel] = mx;
    __shared__ float red[256];
    red[threadIdx.x] = mx;
    __syncthreads();
    for (int st = 128; st > 0; st >>= 1) {
        if (threadIdx.x < st) red[threadIdx.x] += red[threadIdx.x + st];
        __syncthreads();
    }
    if (threadIdx.x == 0) {
        atomicAdd(cnt, red[0]);
        if (cntb) atomicAdd(&cntb[voxel >> lbatch], red[0]);
    }
}

// ---------------- LDS-tiled weight transpose: [27][CIN][COUT] f32 -> [27][COUT][CIN] f16
__global__ __launch_bounds__(256) void wtrans_tiled(const float* __restrict__ w,
                                                    _Float16* __restrict__ o,
                                                    int CIN, int COUT, int ntci, int ntco) {
    __shared__ float tile[32][33];
    int bi = blockIdx.x;
    int tc = bi % ntco;
    int rest = bi / ntco;
    int ti = rest % ntci;
    int tap = rest / ntci;
    int ci0 = ti * 32, co0 = tc * 32;
    const float* src = w + (size_t)tap * CIN * COUT;
    int cc = threadIdx.x & 31, rr = threadIdx.x >> 5;
#pragma unroll
    for (int p = 0; p < 4; ++p) {
        int ci = ci0 + p * 8 + rr, co = co0 + cc;
        tile[p * 8 + rr][cc] = (ci < CIN && co < COUT) ? src[(size_t)ci * COUT + co] : 0.f;
    }
    __syncthreads();
    _Float16* dst = o + (size_t)tap * CIN * COUT;
#pragma unroll
    for (int p = 0; p < 4; ++p) {
        int co = co0 + p * 8 + rr, ci = ci0 + cc;
        if (co < COUT && ci < CIN) dst[(size_t)co * CIN + ci] = (_Float16)tile[cc][p * 8 + rr];
    }
}

// ---------------- conv1a: Cin=1, Cout=16, stride 2 (VALU) ----------
__global__ __launch_bounds__(256) void conv1a_kernel(const float* __restrict__ x,
                                                     const int* __restrict__ mask,
                                                     const float* __restrict__ w,
                                                     const float* __restrict__ m1,
                                                     _Float16* __restrict__ out) {
    int voxel = blockIdx.x * 256 + threadIdx.x;  // 4 * 64^3
    int wo = voxel & 63, ho = (voxel >> 6) & 63, dd = (voxel >> 12) & 63, b = voxel >> 18;
    float acc[16];
#pragma unroll
    for (int i = 0; i < 16; ++i) acc[i] = 0.f;
    for (int kd = 0; kd < 3; ++kd) {
        int id = 2 * dd + kd - 1;
        if ((unsigned)id >= 128u) continue;
        for (int kh = 0; kh < 3; ++kh) {
            int ih = 2 * ho + kh - 1;
            if ((unsigned)ih >= 128u) continue;
            for (int kw = 0; kw < 3; ++kw) {
                int iw = 2 * wo + kw - 1;
                if ((unsigned)iw >= 128u) continue;
                size_t idx = ((size_t)((b * 128 + id) * 128 + ih)) * 128 + iw;
                float xv = x[idx] * (float)mask[idx];
                const float* wp = w + ((kd * 3 + kh) * 3 + kw) * 16;
#pragma unroll
                for (int co = 0; co < 16; ++co) acc[co] = fmaf(xv, wp[co], acc[co]);
            }
        }
    }
    float m = m1[voxel];
    _Float16* op = out + (size_t)voxel * 16;
#pragma unroll
    for (int co = 0; co < 16; ++co) op[co] = (_Float16)(acc[co] * m);
}

// ---------------- unified MFMA implicit-GEMM conv ----------------
template <int CIN, int COUT, int NTILE, int STRIDE, int NIN, int NOUT,
          int TW, int LTW, int TH, int LTH, int TD, int WM>
__global__ __launch_bounds__(256, 2) void conv_mfma(const _Float16* __restrict__ in,
                                                    const _Float16* __restrict__ wt,
                                                    const float* __restrict__ mout,
                                                    _Float16* __restrict__ out,
                                                    const _Float16* __restrict__ zbuf) {
    constexpr int M = TW * TH * TD;
    constexpr int KC = (CIN >= 32) ? 32 : 16;
    constexpr int LVPI = (KC == 32) ? 4 : 5;     // log2 rows/voxels per 1KiB block
    constexpr int VPI = 1 << LVPI;
    constexpr int HW_ = (TW - 1) * STRIDE + 3;
    constexpr int HH_ = (TH - 1) * STRIDE + 3;
    constexpr int HD_ = (TD - 1) * STRIDE + 3;
    constexpr int HV = HW_ * HH_ * HD_;
    constexpr int NIH = (HV + VPI - 1) / VPI;
    constexpr int HVP = NIH * VPI;
    constexpr int WN = 4 / WM;
    constexpr int WMT = M / WM;
    constexpr int WNT = NTILE / WN;
    constexpr int NAF = WMT / 16;
    constexpr int NBF = WNT / 16;
    constexpr int NBLK = COUT / NTILE;
    constexpr int NTW = NOUT / TW, NTH = NOUT / TH, NTD = NOUT / TD;
    constexpr int NUMM = 4 * NTW * NTH * NTD;
    // B tile layout: blocks of VPI rows x KC halves; RB row-blocks, each 512
    // halves (1 KiB). Buffer stride is RB*512 halves (NOT NTILE*KC: when
    // NTILE < VPI the ck>0 sub-blocks still sit at ck*VPI*8 within the block).
    constexpr int RB = (NTILE + VPI - 1) / VPI;
    constexpr int BSTR = RB * 512;                // halves per B buffer
    constexpr int NCHK = RB * 64;                 // 16B chunks per B buffer
    constexpr int J = (NCHK + 255) / 256;         // ldB iterations per wave

    using Frag = typename FragSel<KC>::T;

    __shared__ __align__(16) _Float16 halo[HVP * KC];
    __shared__ __align__(16) _Float16 bbuf[2 * BSTR];

    int bid = blockIdx.x;
    int nblk = (NBLK > 1) ? bid / NUMM : 0;
    int mblk = (NBLK > 1) ? bid % NUMM : bid;
    int tw = mblk % NTW;
    int th = (mblk / NTW) % NTH;
    int td = (mblk / (NTW * NTH)) % NTD;
    int b = mblk / (NTW * NTH * NTD);
    int d0 = td * TD * STRIDE - 1, h0 = th * TH * STRIDE - 1, w0 = tw * TW * STRIDE - 1;

    int tid = threadIdx.x;
    int wv = tid >> 6, lane = tid & 63, m16 = lane & 15, quad = lane >> 4;
    int wm_ = wv % WM, wn_ = wv / WM;

    // per-lane A voxel bases within halo
    int abase[NAF];
#pragma unroll
    for (int r = 0; r < NAF; ++r) {
        int vloc = wm_ * WMT + r * 16 + m16;
        int vw = vloc & (TW - 1), vh = (vloc >> LTW) & (TH - 1), vd = vloc >> (LTW + LTH);
        abase[r] = ((vd * STRIDE) * HH_ + vh * STRIDE) * HW_ + vw * STRIDE;
    }
    // B fragment offsets (halves), layout: [rowblk][ck][row%VPI][8]
    int boffs[NBF];
#pragma unroll
    for (int f = 0; f < NBF; ++f) {
        int R = wn_ * WNT + f * 16 + m16;
        if constexpr (KC == 32)
            boffs[f] = (R >> 4) * 512 + quad * 128 + (R & 15) * 8;
        else
            boffs[f] = (R >> 5) * 512 + (quad >> 1) * 256 + (R & 31) * 8 + (quad & 1) * 4;
    }

    f32x4 acc[NAF][NBF];
#pragma unroll
    for (int r = 0; r < NAF; ++r)
#pragma unroll
        for (int f = 0; f < NBF; ++f) acc[r][f] = (f32x4){0.f, 0.f, 0.f, 0.f};

    // halo stage: layout block i: [ck][voxel][8 halves]
    auto stage_halo = [&](int c0) {
        int sl = lane & (VPI - 1);
        int ck = lane >> LVPI;
        for (int i = wv; i < NIH; i += 4) {
            int hv = i * VPI + sl;
            int hw = hv % HW_;
            int t2 = hv / HW_;
            int hh = t2 % HH_;
            int hd = t2 / HH_;
            int d = d0 + hd, h = h0 + hh, w = w0 + hw;
            bool ok = (hv < HV) && ((unsigned)d < (unsigned)NIN) &&
                      ((unsigned)h < (unsigned)NIN) && ((unsigned)w < (unsigned)NIN);
            const _Float16* g =
                ok ? in + ((size_t)(((b * NIN + d) * NIN + h) * NIN + w)) * CIN + c0 + ck * 8
                   : zbuf;
            gld16(g, &halo[i * VPI * KC]);
        }
    };

    // B tile load to regs / store regs to LDS
    auto ldB = [&](int tap, int c0, f16x8* regs) {
        const _Float16* wb = wt + (size_t)tap * COUT * CIN + (size_t)nblk * NTILE * CIN + c0;
        int rl = lane & (VPI - 1);
        int ck = lane >> LVPI;
#pragma unroll
        for (int j = 0; j < J; ++j) {
            int r = (j * 4 + wv) * VPI + rl;
            if (r < NTILE) regs[j] = *(const f16x8*)(wb + (size_t)r * CIN + ck * 8);
        }
    };
    auto wrB = [&](int buf, f16x8* regs) {
        _Float16* bp = &bbuf[buf * BSTR];
#pragma unroll
        for (int j = 0; j < J; ++j) {
            int c = (j * 4 + wv) * 64 + lane;
            if (c < NCHK) *(f16x8*)(bp + c * 8) = regs[j];
        }
    };

    f16x8 rA[J], rB[J];

    for (int c0 = 0; c0 < CIN; c0 += KC) {
        if (c0) __syncthreads();        // all reads of previous halo/bbuf done
        stage_halo(c0);                 // global_load_lds
        ldB(0, c0, rA);
        wrB(0, rA);                     // compiler waits vmcnt for rA
        ldB(1, c0, rB);                 // prefetch tap 1
        __syncthreads();                // drains halo glds + ds_write

#pragma unroll 1
        for (int t = 0; t < 27; ++t) {
            int kd = t / 9, kh = (t % 9) / 3, kw = t % 3;
            int tapv = (kd * HH_ + kh) * HW_ + kw;
            Frag a[NAF], bf[NBF];
#pragma unroll
            for (int r = 0; r < NAF; ++r) {
                int hv = abase[r] + tapv;
                int off;
                if constexpr (KC == 32)
                    off = (hv >> 4) * 512 + quad * 128 + (hv & 15) * 8;
                else
                    off = (hv >> 5) * 512 + (quad >> 1) * 256 + (hv & 31) * 8 + (quad & 1) * 4;
                a[r] = *(const Frag*)&halo[off];
            }
            const _Float16* bp = &bbuf[(t & 1) * BSTR];
#pragma unroll
            for (int f = 0; f < NBF; ++f) bf[f] = *(const Frag*)&bp[boffs[f]];
#pragma unroll
            for (int r = 0; r < NAF; ++r)
#pragma unroll
                for (int f = 0; f < NBF; ++f) acc[r][f] = mfma16(a[r], bf[f], acc[r][f]);

            if (t < 26) {
                if ((t & 1) == 0) {     // even tap: rB holds tap t+1
                    wrB((t + 1) & 1, rB);
                    if (t + 2 < 27) ldB(t + 2, c0, rA);
                } else {                // odd tap: rA holds tap t+1
                    wrB((t + 1) & 1, rA);
                    if (t + 2 < 27) ldB(t + 2, c0, rB);
                }
                lgkm_barrier();         // LDS-only drain; prefetch stays in flight
            }
        }
    }

    // epilogue: C/D col = m16 (cout), row = quad*4 + j (voxel within frag)
    int n0 = nblk * NTILE + wn_ * WNT + m16;
#pragma unroll
    for (int r = 0; r < NAF; ++r) {
#pragma unroll
        for (int j = 0; j < 4; ++j) {
            int vloc = wm_ * WMT + r * 16 + quad * 4 + j;
            int vw = vloc & (TW - 1), vh = (vloc >> LTW) & (TH - 1), vd = vloc >> (LTW + LTH);
            int od = td * TD + vd, oh = th * TH + vh, ow = tw * TW + vw;
            size_t gvox = ((size_t)((b * NOUT + od) * NOUT + oh)) * NOUT + ow;
            float mv = mout[gvox];
            _Float16* op = out + gvox * COUT + n0;
#pragma unroll
            for (int f = 0; f < NBF; ++f) op[f * 16] = (_Float16)(acc[r][f][j] * mv);
        }
    }
}

// ---------------- BN stats: vectorized f16x8, per-channel sum/sumsq ---------
template <int C>
__global__ __launch_bounds__(256) void bn_stats_v(const _Float16* __restrict__ x,
                                                  long n, float* __restrict__ stats) {
    constexpr int G = C / 8;
    float s[8], q[8];
#pragma unroll
    for (int k = 0; k < 8; ++k) { s[k] = 0.f; q[k] = 0.f; }
    long stride = (long)gridDim.x * 2048;
    for (long i = ((long)blockIdx.x * 256 + threadIdx.x) * 8; i < n; i += stride) {
        f16x8 v = *(const f16x8*)(x + i);
#pragma unroll
        for (int k = 0; k < 8; ++k) {
            float f = (float)v[k];
            s[k] += f;
            q[k] += f * f;
        }
    }
    __shared__ float red[256 * 16];
#pragma unroll
    for (int k = 0; k < 8; ++k) {
        red[threadIdx.x * 16 + k] = s[k];
        red[threadIdx.x * 16 + 8 + k] = q[k];
    }
    __syncthreads();
    for (int st = 128; st >= G; st >>= 1) {
        if (threadIdx.x < st) {
#pragma unroll
            for (int k = 0; k < 16; ++k)
                red[threadIdx.x * 16 + k] += red[(threadIdx.x + st) * 16 + k];
        }
        __syncthreads();
    }
    if (threadIdx.x < G) {
        int cb = threadIdx.x * 8;
#pragma unroll
        for (int k = 0; k < 8; ++k) {
            atomicAdd(&stats[cb + k], red[threadIdx.x * 16 + k]);
            atomicAdd(&stats[C + cb + k], red[threadIdx.x * 16 + 8 + k]);
        }
    }
}

// ---------------- BN apply + ELU + mask (coef computed in-block) ------------
template <int C, int LOGC>
__global__ __launch_bounds__(256) void bn_apply_v(_Float16* __restrict__ x,
                                                  const float* __restrict__ m,
                                                  const float* __restrict__ stats,
                                                  const float* __restrict__ cnt,
                                                  const float* __restrict__ gamma,
                                                  const float* __restrict__ beta, long n) {
    __shared__ float sc[2 * C];
    float cn = *cnt;
    for (int c = threadIdx.x; c < C; c += 256) {
        float mean = stats[c] / cn;
        float var = stats[C + c] / cn - mean * mean;
        float s = rsqrtf(var + EPSV) * gamma[c];
        sc[c] = s;
        sc[C + c] = beta[c] - mean * s;
    }
    __syncthreads();
    long stride = (long)gridDim.x * 2048;
    for (long i8 = ((long)blockIdx.x * 256 + threadIdx.x) * 8; i8 < n; i8 += stride) {
        int c = (int)(i8 & (C - 1));
        long v = i8 >> LOGC;
        f16x8 xv = *(const f16x8*)(x + i8);
        float mv = m[v];
        f16x8 o;
#pragma unroll
        for (int k = 0; k < 8; ++k) {
            float xh = (float)xv[k] * sc[c + k] + sc[C + c + k];
            float e = xh > 0.f ? xh : expm1f(xh);
            o[k] = (_Float16)(e * mv);
        }
        *(f16x8*)(x + i8) = o;
    }
}

// ---------------- global masked mean pool (sums) ----------------
__global__ __launch_bounds__(256) void gpool_kernel(const _Float16* __restrict__ h,
                                                    float* __restrict__ pooled) {
    int b = blockIdx.x >> 3, seg = blockIdx.x & 7;  // 8 segments of 512 voxels
    int ch = (threadIdx.x & 63) * 8;
    int v0 = threadIdx.x >> 6;
    float s[8];
#pragma unroll
    for (int k = 0; k < 8; ++k) s[k] = 0.f;
    for (int v = v0; v < 512; v += 4) {
        const _Float16* p = h + ((size_t)(b * 4096 + seg * 512 + v)) * 512 + ch;
        f16x8 xv = *(const f16x8*)p;
#pragma unroll
        for (int k = 0; k < 8; ++k) s[k] += (float)xv[k];
    }
#pragma unroll
    for (int k = 0; k < 8; ++k) atomicAdd(&pooled[b * 512 + ch + k], s[k]);
}

// ---------------- heads ----------------
__global__ __launch_bounds__(256) void head_kernel(const float* __restrict__ pooled,
                                                   const float* __restrict__ cntb,
                                                   const float* __restrict__ wm,
                                                   const float* __restrict__ bm,
                                                   const float* __restrict__ wv,
                                                   const float* __restrict__ bv,
                                                   float* __restrict__ out) {
    int t = blockIdx.x * 256 + threadIdx.x;  // 4096
    int which = t >> 11;
    int b = (t >> 9) & 3;
    int j = t & 511;
    const float* W = which ? wv : wm;
    float bias = which ? bv[j] : bm[j];
    const float* p = pooled + b * 512;
    float s = 0.f;
    for (int c = 0; c < 512; ++c) s = fmaf(p[c], W[c * 512 + j], s);
    out[t] = s / cntb[b] + bias;
}

// ---------------------------------------------------------------------------
extern "C" void kernel_launch(void* const* d_in, const int* in_sizes, int n_in,
                              void* d_out, int out_size, void* d_ws, size_t ws_size,
                              hipStream_t stream) {
    const float* x   = (const float*)d_in[0];
    const int* mask  = (const int*)d_in[1];
    const float* w1a = (const float*)d_in[2];
    const float* g1a = (const float*)d_in[3];
    const float* b1a = (const float*)d_in[4];
    const float* w1b = (const float*)d_in[5];
    const float* g1b = (const float*)d_in[6];
    const float* b1b = (const float*)d_in[7];
    const float* w2a = (const float*)d_in[8];
    const float* g2a = (const float*)d_in[9];
    const float* b2a = (const float*)d_in[10];
    const float* w2b = (const float*)d_in[11];
    const float* g2b = (const float*)d_in[12];
    const float* b2b = (const float*)d_in[13];
    const float* w3a = (const float*)d_in[14];
    const float* g3a = (const float*)d_in[15];
    const float* b3a = (const float*)d_in[16];
    const float* w3b = (const float*)d_in[17];
    const float* g3b = (const float*)d_in[18];
    const float* b3b = (const float*)d_in[19];
    const float* wm  = (const float*)d_in[20];
    const float* bm  = (const float*)d_in[21];
    const float* wv  = (const float*)d_in[22];
    const float* bv  = (const float*)d_in[23];
    float* out = (float*)d_out;

    char* ws = (char*)d_ws;
    _Float16* A  = (_Float16*)(ws + 0);            // 32 MiB activations ping
    _Float16* Bb = (_Float16*)(ws + 33554432);     // 32 MiB activations pong
    _Float16* w1bh = (_Float16*)(ws + 67108864);
    _Float16* w2ah = (_Float16*)(ws + 67125248);
    _Float16* w2bh = (_Float16*)(ws + 67182592);
    _Float16* w3ah = (_Float16*)(ws + 67403776);
    _Float16* w3bh = (_Float16*)(ws + 69173248);
    float* m1 = (float*)(ws + 83329024);           // 4 MiB
    float* m2 = (float*)(ws + 87523328);           // 512 KiB
    float* m3 = (float*)(ws + 88047616);           // 64 KiB
    float* stats  = (float*)(ws + 88113152);       // 6 x 4 KiB
    float* counts = (float*)(ws + 88137728);       // 64 B
    float* pooled = (float*)(ws + 88137792);       // 8 KiB
    _Float16* zbuf = (_Float16*)(ws + 88145984);   // 256 B zeros

    _Float16* h1a = A;
    _Float16* h1b = Bb;
    _Float16* h2a = A;
    _Float16* h2b = Bb;
    _Float16* h3a = A;
    _Float16* h3b = Bb;

    // one memset: stats(24576) + counts(64) + pooled(8192) + zbuf(256)
    hipMemsetAsync(stats, 0, 24576 + 64 + 8192 + 256, stream);

    // masks + fused counts
    pool0_kernel<<<4096, 256, 0, stream>>>(mask, m1, counts + 0);
    poolf_kernel<<<512, 256, 0, stream>>>(m1, m2, 32, 5, counts + 1, nullptr, 0);
    poolf_kernel<<<64, 256, 0, stream>>>(m2, m3, 16, 4, counts + 2, counts + 4, 12);

    // weight transposes (LDS-tiled)
    wtrans_tiled<<<27, 256, 0, stream>>>(w1b, w1bh, 16, 16, 1, 1);
    wtrans_tiled<<<54, 256, 0, stream>>>(w2a, w2ah, 16, 64, 1, 2);
    wtrans_tiled<<<108, 256, 0, stream>>>(w2b, w2bh, 64, 64, 2, 2);
    wtrans_tiled<<<864, 256, 0, stream>>>(w3a, w3ah, 64, 512, 2, 16);
    wtrans_tiled<<<6912, 256, 0, stream>>>(w3b, w3bh, 512, 512, 16, 16);

    // ---- block 1 ----
    conv1a_kernel<<<4096, 256, 0, stream>>>(x, mask, w1a, m1, h1a);
    bn_stats_v<16><<<512, 256, 0, stream>>>(h1a, 16777216L, stats + 0 * 1024);
    bn_apply_v<16, 4><<<2048, 256, 0, stream>>>(h1a, m1, stats + 0 * 1024, counts + 0,
                                                g1a, b1a, 16777216L);

    conv_mfma<16, 16, 16, 1, 64, 64, 8, 3, 4, 2, 4, 4>
        <<<8192, 256, 0, stream>>>(h1a, w1bh, m1, h1b, zbuf);
    bn_stats_v<16><<<512, 256, 0, stream>>>(h1b, 16777216L, stats + 1 * 1024);
    bn_apply_v<16, 4><<<2048, 256, 0, stream>>>(h1b, m1, stats + 1 * 1024, counts + 0,
                                                g1b, b1b, 16777216L);

    // ---- block 2 ----
    conv_mfma<16, 64, 64, 2, 64, 32, 4, 2, 4, 2, 4, 2>
        <<<2048, 256, 0, stream>>>(h1b, w2ah, m2, h2a, zbuf);
    bn_stats_v<64><<<512, 256, 0, stream>>>(h2a, 8388608L, stats + 2 * 1024);
    bn_apply_v<64, 6><<<1024, 256, 0, stream>>>(h2a, m2, stats + 2 * 1024, counts + 1,
                                                g2a, b2a, 8388608L);

    conv_mfma<64, 64, 64, 1, 32, 32, 8, 3, 4, 2, 4, 2>
        <<<1024, 256, 0, stream>>>(h2a, w2bh, m2, h2b, zbuf);
    bn_stats_v<64><<<512, 256, 0, stream>>>(h2b, 8388608L, stats + 3 * 1024);
    bn_apply_v<64, 6><<<1024, 256, 0, stream>>>(h2b, m2, stats + 3 * 1024, counts + 1,
                                                g2b, b2b, 8388608L);

    // ---- block 3 ----
    conv_mfma<64, 512, 128, 2, 32, 16, 4, 2, 4, 2, 4, 2>
        <<<1024, 256, 0, stream>>>(h2b, w3ah, m3, h3a, zbuf);
    bn_stats_v<512><<<512, 256, 0, stream>>>(h3a, 8388608L, stats + 4 * 1024);
    bn_apply_v<512, 9><<<512, 256, 0, stream>>>(h3a, m3, stats + 4 * 1024, counts + 2,
                                                g3a, b3a, 8388608L);

    conv_mfma<512, 512, 128, 1, 16, 16, 8, 3, 4, 2, 4, 2>
        <<<512, 256, 0, stream>>>(h3a, w3bh, m3, h3b, zbuf);
    bn_stats_v<512><<<512, 256, 0, stream>>>(h3b, 8388608L, stats + 5 * 1024);
    bn_apply_v<512, 9><<<512, 256, 0, stream>>>(h3b, m3, stats + 5 * 1024, counts + 2,
                                                g3b, b3b, 8388608L);

    // ---- pool + heads ----
    gpool_kernel<<<32, 256, 0, stream>>>(h3b, pooled);
    head_kernel<<<16, 256, 0, stream>>>(pooled, counts + 4, wm, bm, wv, bv, out);
}